// Round 7
// baseline (443.054 us; speedup 1.0000x reference)
//
#include <hip/hip_runtime.h>
#include <hip/hip_bf16.h>

#define NN 100000
#define EE 1600000

typedef __attribute__((ext_vector_type(8))) short short8;
typedef __attribute__((ext_vector_type(4))) float f32x4;

__device__ __forceinline__ unsigned short f2bfu(float f) {
    __hip_bfloat16 h = __float2bfloat16(f);
    return *reinterpret_cast<unsigned short*>(&h);
}
__device__ __forceinline__ float bflo(unsigned int u) {
    return __uint_as_float(u << 16);
}
__device__ __forceinline__ float bfhi(unsigned int u) {
    return __uint_as_float(u & 0xffff0000u);
}

// ---------------- workspace layout (bytes) ----------------
// WCT 0 (49152) | BC 49152 | Z0 65536 (12.8e6) | ZA 12865536 | ZB 25665536
// DINV 38465536 | CNT 38865536 | PTR 39265536 | BSUM 39665664 | PTR2 39667712
// CEV 40067840 | total ~52.9 MB   (z rows padded to 64 bf16 = one 128B line)

__global__ void wct_kernel(const float* __restrict__ W1, const float* __restrict__ W2,
                           const float* __restrict__ b1, short* __restrict__ WcT,
                           float* __restrict__ bc) {
    int t = blockIdx.x * 256 + threadIdx.x;
    if (t < 48 * 512) {
        int j = t >> 9, k = t & 511;
        float s = 0.f;
        if (j < 40)
            for (int i = 0; i < 128; ++i) s = fmaf(W1[k * 128 + i], W2[i * 40 + j], s);
        WcT[j * 512 + k] = (short)f2bfu(s);
    } else if (t < 48 * 512 + 48) {
        int j = t - 48 * 512;
        float s = 0.f;
        if (j < 40)
            for (int i = 0; i < 128; ++i) s = fmaf(b1[i], W2[i * 40 + j], s);
        bc[j] = s;
    }
}

// z0 = bf16( x @ Wc + bc ), rows padded to 64 (cols 40..47 zeros via WcT pad, 48..63 explicit 0)
__global__ __launch_bounds__(256) void gemm_z0(const float* __restrict__ x,
                                               const short* __restrict__ WcT,
                                               const float* __restrict__ bc,
                                               unsigned short* __restrict__ z0) {
    const int tid = threadIdx.x;
    const int lane = tid & 63;
    const int wave = tid >> 6;
    const int rbase = blockIdx.x * 64 + wave * 16;
    const int row = rbase + (lane & 15);
    const int kc = lane >> 4;
    const bool rok = row < NN;

    f32x4 acc0 = {0.f, 0.f, 0.f, 0.f};
    f32x4 acc1 = {0.f, 0.f, 0.f, 0.f};
    f32x4 acc2 = {0.f, 0.f, 0.f, 0.f};

    const float* xrow = x + (size_t)row * 512 + kc * 8;
    const short* bp0 = WcT + (size_t)(lane & 15) * 512 + kc * 8;
    const short* bp1 = bp0 + 16 * 512;
    const short* bp2 = bp0 + 32 * 512;

    for (int k0 = 0; k0 < 512; k0 += 32) {
        float4 p0 = {0.f, 0.f, 0.f, 0.f}, p1 = {0.f, 0.f, 0.f, 0.f};
        if (rok) {
            p0 = *reinterpret_cast<const float4*>(xrow + k0);
            p1 = *reinterpret_cast<const float4*>(xrow + k0 + 4);
        }
        short8 a;
        a[0] = (short)f2bfu(p0.x); a[1] = (short)f2bfu(p0.y);
        a[2] = (short)f2bfu(p0.z); a[3] = (short)f2bfu(p0.w);
        a[4] = (short)f2bfu(p1.x); a[5] = (short)f2bfu(p1.y);
        a[6] = (short)f2bfu(p1.z); a[7] = (short)f2bfu(p1.w);
        short8 b0 = *reinterpret_cast<const short8*>(bp0 + k0);
        short8 b1 = *reinterpret_cast<const short8*>(bp1 + k0);
        short8 b2 = *reinterpret_cast<const short8*>(bp2 + k0);
        acc0 = __builtin_amdgcn_mfma_f32_16x16x32_bf16(a, b0, acc0, 0, 0, 0);
        acc1 = __builtin_amdgcn_mfma_f32_16x16x32_bf16(a, b1, acc1, 0, 0, 0);
        acc2 = __builtin_amdgcn_mfma_f32_16x16x32_bf16(a, b2, acc2, 0, 0, 0);
    }

    const int cb = lane & 15;
    const int rr = rbase + (lane >> 4) * 4;
#pragma unroll
    for (int q = 0; q < 4; ++q) {
        int r = rr + q;
        if (r < NN) {
            z0[(size_t)r * 64 + cb] = f2bfu(acc0[q] + bc[cb]);
            z0[(size_t)r * 64 + cb + 16] = f2bfu(acc1[q] + bc[cb + 16]);
            z0[(size_t)r * 64 + cb + 32] = f2bfu(acc2[q] + bc[cb + 32]);
            z0[(size_t)r * 64 + cb + 48] = 0;
        }
    }
}

__global__ void count_kernel(const int* __restrict__ eidx, int* __restrict__ counts) {
    int e = blockIdx.x * 256 + threadIdx.x;
    if (e < EE) atomicAdd(&counts[eidx[EE + e]], 1);
}

__global__ void scan1(const int* __restrict__ counts, int* __restrict__ ptr,
                      int* __restrict__ bsum) {
    __shared__ int s[256];
    int tid = threadIdx.x;
    int i = blockIdx.x * 256 + tid;
    int v = (i < NN) ? counts[i] : 0;
    s[tid] = v;
    __syncthreads();
    for (int off = 1; off < 256; off <<= 1) {
        int t = (tid >= off) ? s[tid - off] : 0;
        __syncthreads();
        s[tid] += t;
        __syncthreads();
    }
    if (i < NN) ptr[i] = s[tid] - v;
    if (tid == 255) bsum[blockIdx.x] = s[255];
}

__global__ void scan2(int* __restrict__ bsum) {
    __shared__ int s[512];
    int tid = threadIdx.x;
    int v = (tid < 391) ? bsum[tid] : 0;
    s[tid] = v;
    __syncthreads();
    for (int off = 1; off < 512; off <<= 1) {
        int t = (tid >= off) ? s[tid - off] : 0;
        __syncthreads();
        s[tid] += t;
        __syncthreads();
    }
    if (tid < 391) bsum[tid] = s[tid] - v;
}

__global__ void scan3(int* __restrict__ ptr, const int* __restrict__ bsum,
                      const int* __restrict__ counts, float* __restrict__ dinvp,
                      int* __restrict__ ptr2) {
    int i = blockIdx.x * 256 + threadIdx.x;
    if (i < NN) {
        int p = ptr[i] + bsum[blockIdx.x];
        ptr[i] = p;
        ptr2[i] = p;
        dinvp[i] = rsqrtf(1.0f + (float)counts[i]);
    }
    if (i == 0) { ptr[NN] = EE; ptr2[NN] = EE; }
}

__global__ void scatter_kernel(const int* __restrict__ eidx,
                               const float* __restrict__ dinvp, int* __restrict__ ptr2,
                               int2* __restrict__ cev) {
    int e = blockIdx.x * 256 + threadIdx.x;
    if (e < EE) {
        int r = eidx[e];
        int c = eidx[EE + e];
        int pos = atomicAdd(&ptr2[c], 1);
        cev[pos] = make_int2(r, __float_as_int(dinvp[r]));
    }
}

// one wave per node; 4 edges in parallel across 16-lane groups,
// each load instr = 4 distinct 128B rows in flight.
__global__ __launch_bounds__(256) void propagate(const unsigned short* __restrict__ zcur,
                                                 const unsigned short* __restrict__ z0q,
                                                 unsigned short* __restrict__ znb,
                                                 float* __restrict__ outf,
                                                 const int* __restrict__ ptr,
                                                 const int2* __restrict__ cev,
                                                 const float* __restrict__ dinvp,
                                                 const float* __restrict__ b2, int last) {
    const int lane = threadIdx.x & 63;
    const int node = blockIdx.x * 4 + (threadIdx.x >> 6);
    const int t = lane & 15;   // row segment (features t*4..t*4+3)
    const int g = lane >> 4;   // edge group
    const int t8 = t * 8;
    const int g4 = g * 4;

    int beg = __builtin_amdgcn_readfirstlane(ptr[node]);
    int end = __builtin_amdgcn_readfirstlane(ptr[node + 1]);
    const int deg = end - beg;
    int m = deg > 64 ? 64 : deg;

    // batch-load edge records; weights zeroed for lanes >= m
    int2 ev = make_int2(0, 0);
    if (m > 0) ev = cev[beg + (lane < m ? lane : m - 1)];
    if (lane >= m) ev.y = 0;

    const float dc = dinvp[node];
    const char* zb = (const char*)zcur;

    // self term counted only by group 0 (groups are summed at the end)
    uint2 ps = *(const uint2*)(zb + (size_t)node * 128 + t8);
    float sg = (g == 0) ? dc : 0.0f;
    float acc0 = sg * bflo(ps.x);
    float acc1 = sg * bfhi(ps.x);
    float acc2 = sg * bflo(ps.y);
    float acc3 = sg * bfhi(ps.y);

    const int nc = (m + 3) >> 2;
    int c = 0;
    for (; c + 4 <= nc; c += 4) {
        int i0 = c * 16 + g4;
        int r0 = __builtin_amdgcn_ds_bpermute(i0, ev.x);
        int r1 = __builtin_amdgcn_ds_bpermute(i0 + 16, ev.x);
        int r2 = __builtin_amdgcn_ds_bpermute(i0 + 32, ev.x);
        int r3 = __builtin_amdgcn_ds_bpermute(i0 + 48, ev.x);
        int w0 = __builtin_amdgcn_ds_bpermute(i0, ev.y);
        int w1 = __builtin_amdgcn_ds_bpermute(i0 + 16, ev.y);
        int w2 = __builtin_amdgcn_ds_bpermute(i0 + 32, ev.y);
        int w3 = __builtin_amdgcn_ds_bpermute(i0 + 48, ev.y);
        uint2 p0 = *(const uint2*)(zb + (size_t)r0 * 128 + t8);
        uint2 p1 = *(const uint2*)(zb + (size_t)r1 * 128 + t8);
        uint2 p2 = *(const uint2*)(zb + (size_t)r2 * 128 + t8);
        uint2 p3 = *(const uint2*)(zb + (size_t)r3 * 128 + t8);
        float W0 = __int_as_float(w0), W1 = __int_as_float(w1);
        float W2 = __int_as_float(w2), W3 = __int_as_float(w3);
        acc0 = fmaf(W0, bflo(p0.x), acc0);
        acc1 = fmaf(W0, bfhi(p0.x), acc1);
        acc2 = fmaf(W0, bflo(p0.y), acc2);
        acc3 = fmaf(W0, bfhi(p0.y), acc3);
        acc0 = fmaf(W1, bflo(p1.x), acc0);
        acc1 = fmaf(W1, bfhi(p1.x), acc1);
        acc2 = fmaf(W1, bflo(p1.y), acc2);
        acc3 = fmaf(W1, bfhi(p1.y), acc3);
        acc0 = fmaf(W2, bflo(p2.x), acc0);
        acc1 = fmaf(W2, bfhi(p2.x), acc1);
        acc2 = fmaf(W2, bflo(p2.y), acc2);
        acc3 = fmaf(W2, bfhi(p2.y), acc3);
        acc0 = fmaf(W3, bflo(p3.x), acc0);
        acc1 = fmaf(W3, bfhi(p3.x), acc1);
        acc2 = fmaf(W3, bflo(p3.y), acc2);
        acc3 = fmaf(W3, bfhi(p3.y), acc3);
    }
    for (; c < nc; ++c) {
        int i0 = c * 16 + g4;
        int r0 = __builtin_amdgcn_ds_bpermute(i0, ev.x);
        int w0 = __builtin_amdgcn_ds_bpermute(i0, ev.y);
        uint2 p0 = *(const uint2*)(zb + (size_t)r0 * 128 + t8);
        float W0 = __int_as_float(w0);
        acc0 = fmaf(W0, bflo(p0.x), acc0);
        acc1 = fmaf(W0, bfhi(p0.x), acc1);
        acc2 = fmaf(W0, bflo(p0.y), acc2);
        acc3 = fmaf(W0, bfhi(p0.y), acc3);
    }

    // ultra-rare: degree > 64, round-robin across groups
    if (deg > 64) {
        for (int e2 = beg + 64 + g; e2 < end; e2 += 4) {
            int2 ee = cev[e2];
            uint2 p = *(const uint2*)(zb + (size_t)ee.x * 128 + t8);
            float w = __int_as_float(ee.y);
            acc0 = fmaf(w, bflo(p.x), acc0);
            acc1 = fmaf(w, bfhi(p.x), acc1);
            acc2 = fmaf(w, bflo(p.y), acc2);
            acc3 = fmaf(w, bfhi(p.y), acc3);
        }
    }

    // butterfly-reduce across the 4 groups (lanes t, t+16, t+32, t+48)
    acc0 += __shfl_xor(acc0, 16, 64); acc0 += __shfl_xor(acc0, 32, 64);
    acc1 += __shfl_xor(acc1, 16, 64); acc1 += __shfl_xor(acc1, 32, 64);
    acc2 += __shfl_xor(acc2, 16, 64); acc2 += __shfl_xor(acc2, 32, 64);
    acc3 += __shfl_xor(acc3, 16, 64); acc3 += __shfl_xor(acc3, 32, 64);

    uint2 pz = *(const uint2*)((const char*)z0q + (size_t)node * 128 + t8);
    float r0v = 0.5f * dc * acc0 + 0.5f * bflo(pz.x);
    float r1v = 0.5f * dc * acc1 + 0.5f * bfhi(pz.x);
    float r2v = 0.5f * dc * acc2 + 0.5f * bflo(pz.y);
    float r3v = 0.5f * dc * acc3 + 0.5f * bfhi(pz.y);

    if (last) {
        if (g == 0 && t < 10) {
            float4 bv = *(const float4*)(b2 + t * 4);
            float4 o;
            o.x = r0v + bv.x; o.y = r1v + bv.y; o.z = r2v + bv.z; o.w = r3v + bv.w;
            *(float4*)(outf + (size_t)node * 40 + t * 4) = o;
        }
    } else {
        if (g == 0) {
            uint2 s;
            s.x = ((unsigned int)f2bfu(r1v) << 16) | f2bfu(r0v);
            s.y = ((unsigned int)f2bfu(r3v) << 16) | f2bfu(r2v);
            *(uint2*)((char*)znb + (size_t)node * 128 + t8) = s;
        }
    }
}

extern "C" void kernel_launch(void* const* d_in, const int* in_sizes, int n_in,
                              void* d_out, int out_size, void* d_ws, size_t ws_size,
                              hipStream_t stream) {
    const float* x  = (const float*)d_in[0];
    const int*   ei = (const int*)d_in[1];
    const float* W1 = (const float*)d_in[2];
    const float* b1 = (const float*)d_in[3];
    const float* W2 = (const float*)d_in[4];
    const float* b2 = (const float*)d_in[5];
    float* out = (float*)d_out;

    char* ws = (char*)d_ws;
    short*          WcT  = (short*)(ws + 0);
    float*          bc   = (float*)(ws + 49152);
    unsigned short* z0   = (unsigned short*)(ws + 65536);
    unsigned short* za   = (unsigned short*)(ws + 12865536);
    unsigned short* zb   = (unsigned short*)(ws + 25665536);
    float*          dinv = (float*)(ws + 38465536);
    int*            cnt  = (int*)(ws + 38865536);
    int*            ptr  = (int*)(ws + 39265536);
    int*            bsum = (int*)(ws + 39665664);
    int*            ptr2 = (int*)(ws + 39667712);
    int2*           cev  = (int2*)(ws + 40067840);

    hipMemsetAsync(cnt, 0, NN * sizeof(int), stream);
    wct_kernel<<<97, 256, 0, stream>>>(W1, W2, b1, WcT, bc);
    count_kernel<<<(EE + 255) / 256, 256, 0, stream>>>(ei, cnt);
    scan1<<<391, 256, 0, stream>>>(cnt, ptr, bsum);
    scan2<<<1, 512, 0, stream>>>(bsum);
    scan3<<<391, 256, 0, stream>>>(ptr, bsum, cnt, dinv, ptr2);
    gemm_z0<<<1563, 256, 0, stream>>>(x, WcT, bc, z0);
    scatter_kernel<<<(EE + 255) / 256, 256, 0, stream>>>(ei, dinv, ptr2, cev);

    propagate<<<25000, 256, 0, stream>>>(z0, z0, zb, out, ptr, cev, dinv, b2, 0);
    propagate<<<25000, 256, 0, stream>>>(zb, z0, za, out, ptr, cev, dinv, b2, 0);
    propagate<<<25000, 256, 0, stream>>>(za, z0, zb, out, ptr, cev, dinv, b2, 0);
    propagate<<<25000, 256, 0, stream>>>(zb, z0, za, out, ptr, cev, dinv, b2, 0);
    propagate<<<25000, 256, 0, stream>>>(za, z0, zb, out, ptr, cev, dinv, b2, 1);
}

// Round 8
// 427.069 us; speedup vs baseline: 1.0374x; 1.0374x over previous
//
#include <hip/hip_runtime.h>
#include <hip/hip_bf16.h>

#define NN 100000
#define EE 1600000
#define HALFN 50000

typedef __attribute__((ext_vector_type(8))) short short8;
typedef __attribute__((ext_vector_type(4))) float f32x4;

__device__ __forceinline__ unsigned short f2bfu(float f) {
    __hip_bfloat16 h = __float2bfloat16(f);
    return *reinterpret_cast<unsigned short*>(&h);
}
__device__ __forceinline__ float bf2f(unsigned short u) {
    return __uint_as_float((unsigned int)u << 16);
}

// ---------------- workspace layout (bytes) ----------------
// WCT 0 (49152) | BC 49152 | Z0 65536 (12.8e6) | ZA 12865536 | ZB 25665536
// DINV 38465536 | CNT 38865536 | PTR 39265536 | BSUM 39665664 | PTR2 39667712
// CEV 40067840 | total ~52.9 MB   (z rows padded to 64 bf16 = one 128B line)

__global__ void wct_kernel(const float* __restrict__ W1, const float* __restrict__ W2,
                           const float* __restrict__ b1, short* __restrict__ WcT,
                           float* __restrict__ bc) {
    int t = blockIdx.x * 256 + threadIdx.x;
    if (t < 48 * 512) {
        int j = t >> 9, k = t & 511;
        float s = 0.f;
        if (j < 40)
            for (int i = 0; i < 128; ++i) s = fmaf(W1[k * 128 + i], W2[i * 40 + j], s);
        WcT[j * 512 + k] = (short)f2bfu(s);
    } else if (t < 48 * 512 + 48) {
        int j = t - 48 * 512;
        float s = 0.f;
        if (j < 40)
            for (int i = 0; i < 128; ++i) s = fmaf(b1[i], W2[i * 40 + j], s);
        bc[j] = s;
    }
}

// z0 = bf16( x @ Wc + bc ), rows padded to 64 (cols 40..47 zeros via WcT pad, 48..63 explicit 0)
__global__ __launch_bounds__(256) void gemm_z0(const float* __restrict__ x,
                                               const short* __restrict__ WcT,
                                               const float* __restrict__ bc,
                                               unsigned short* __restrict__ z0) {
    const int tid = threadIdx.x;
    const int lane = tid & 63;
    const int wave = tid >> 6;
    const int rbase = blockIdx.x * 64 + wave * 16;
    const int row = rbase + (lane & 15);
    const int kc = lane >> 4;
    const bool rok = row < NN;

    f32x4 acc0 = {0.f, 0.f, 0.f, 0.f};
    f32x4 acc1 = {0.f, 0.f, 0.f, 0.f};
    f32x4 acc2 = {0.f, 0.f, 0.f, 0.f};

    const float* xrow = x + (size_t)row * 512 + kc * 8;
    const short* bp0 = WcT + (size_t)(lane & 15) * 512 + kc * 8;
    const short* bp1 = bp0 + 16 * 512;
    const short* bp2 = bp0 + 32 * 512;

    for (int k0 = 0; k0 < 512; k0 += 32) {
        float4 p0 = {0.f, 0.f, 0.f, 0.f}, p1 = {0.f, 0.f, 0.f, 0.f};
        if (rok) {
            p0 = *reinterpret_cast<const float4*>(xrow + k0);
            p1 = *reinterpret_cast<const float4*>(xrow + k0 + 4);
        }
        short8 a;
        a[0] = (short)f2bfu(p0.x); a[1] = (short)f2bfu(p0.y);
        a[2] = (short)f2bfu(p0.z); a[3] = (short)f2bfu(p0.w);
        a[4] = (short)f2bfu(p1.x); a[5] = (short)f2bfu(p1.y);
        a[6] = (short)f2bfu(p1.z); a[7] = (short)f2bfu(p1.w);
        short8 b0 = *reinterpret_cast<const short8*>(bp0 + k0);
        short8 b1 = *reinterpret_cast<const short8*>(bp1 + k0);
        short8 b2 = *reinterpret_cast<const short8*>(bp2 + k0);
        acc0 = __builtin_amdgcn_mfma_f32_16x16x32_bf16(a, b0, acc0, 0, 0, 0);
        acc1 = __builtin_amdgcn_mfma_f32_16x16x32_bf16(a, b1, acc1, 0, 0, 0);
        acc2 = __builtin_amdgcn_mfma_f32_16x16x32_bf16(a, b2, acc2, 0, 0, 0);
    }

    const int cb = lane & 15;
    const int rr = rbase + (lane >> 4) * 4;
#pragma unroll
    for (int q = 0; q < 4; ++q) {
        int r = rr + q;
        if (r < NN) {
            z0[(size_t)r * 64 + cb] = f2bfu(acc0[q] + bc[cb]);
            z0[(size_t)r * 64 + cb + 16] = f2bfu(acc1[q] + bc[cb + 16]);
            z0[(size_t)r * 64 + cb + 32] = f2bfu(acc2[q] + bc[cb + 32]);
            z0[(size_t)r * 64 + cb + 48] = 0;
        }
    }
}

__global__ void count_kernel(const int* __restrict__ eidx, int* __restrict__ counts) {
    int e = blockIdx.x * 256 + threadIdx.x;
    if (e < EE) atomicAdd(&counts[eidx[EE + e]], 1);
}

__global__ void scan1(const int* __restrict__ counts, int* __restrict__ ptr,
                      int* __restrict__ bsum) {
    __shared__ int s[256];
    int tid = threadIdx.x;
    int i = blockIdx.x * 256 + tid;
    int v = (i < NN) ? counts[i] : 0;
    s[tid] = v;
    __syncthreads();
    for (int off = 1; off < 256; off <<= 1) {
        int t = (tid >= off) ? s[tid - off] : 0;
        __syncthreads();
        s[tid] += t;
        __syncthreads();
    }
    if (i < NN) ptr[i] = s[tid] - v;
    if (tid == 255) bsum[blockIdx.x] = s[255];
}

__global__ void scan2(int* __restrict__ bsum) {
    __shared__ int s[512];
    int tid = threadIdx.x;
    int v = (tid < 391) ? bsum[tid] : 0;
    s[tid] = v;
    __syncthreads();
    for (int off = 1; off < 512; off <<= 1) {
        int t = (tid >= off) ? s[tid - off] : 0;
        __syncthreads();
        s[tid] += t;
        __syncthreads();
    }
    if (tid < 391) bsum[tid] = s[tid] - v;
}

__global__ void scan3(int* __restrict__ ptr, const int* __restrict__ bsum,
                      const int* __restrict__ counts, float* __restrict__ dinvp,
                      int* __restrict__ ptr2) {
    int i = blockIdx.x * 256 + threadIdx.x;
    if (i < NN) {
        int p = ptr[i] + bsum[blockIdx.x];
        ptr[i] = p;
        ptr2[i] = p;
        dinvp[i] = rsqrtf(1.0f + (float)counts[i]);
    }
    if (i == 0) { ptr[NN] = EE; ptr2[NN] = EE; }
}

__global__ void scatter_kernel(const int* __restrict__ eidx,
                               const float* __restrict__ dinvp, int* __restrict__ ptr2,
                               int2* __restrict__ cev) {
    int e = blockIdx.x * 256 + threadIdx.x;
    if (e < EE) {
        int r = eidx[e];
        int c = eidx[EE + e];
        int pos = atomicAdd(&ptr2[c], 1);
        cev[pos] = make_int2(r, __float_as_int(dinvp[r]));
    }
}

// 2 nodes per wave; branch-free chunks of 8 edges per node, 16 gathers in flight.
// 32-bit gather offsets (uniform-base + voffset form); 8 waves/SIMD pinned.
__global__ __launch_bounds__(256, 8) void propagate(const unsigned short* __restrict__ zcur,
                                                    const unsigned short* __restrict__ z0q,
                                                    unsigned short* __restrict__ znb,
                                                    float* __restrict__ outf,
                                                    const int* __restrict__ ptr,
                                                    const int2* __restrict__ cev,
                                                    const float* __restrict__ dinvp,
                                                    const float* __restrict__ b2, int last) {
    const int lane = threadIdx.x & 63;
    const int wid = blockIdx.x * 4 + (threadIdx.x >> 6);
    const int n0 = wid, n1 = wid + HALFN;

    int beg0 = __builtin_amdgcn_readfirstlane(ptr[n0]);
    int end0 = __builtin_amdgcn_readfirstlane(ptr[n0 + 1]);
    int beg1 = __builtin_amdgcn_readfirstlane(ptr[n1]);
    int end1 = __builtin_amdgcn_readfirstlane(ptr[n1 + 1]);
    const float dc0 = dinvp[n0], dc1 = dinvp[n1];

    int m0 = end0 - beg0; if (m0 > 64) m0 = 64;
    int m1 = end1 - beg1; if (m1 > 64) m1 = 64;

    // batch loads: rows clamped to a valid entry, weights zeroed for lanes >= m
    int idx0 = beg0 + (lane < m0 ? lane : m0 - 1); if (idx0 < 0) idx0 = 0;
    int idx1 = beg1 + (lane < m1 ? lane : m1 - 1); if (idx1 < 0) idx1 = 0;
    int2 ev0 = cev[idx0];
    int2 ev1 = cev[idx1];
    if (lane >= m0) ev0.y = 0;
    if (lane >= m1) ev1.y = 0;

    const float self0 = bf2f(zcur[(unsigned)(n0 * 64 + lane)]);
    const float self1 = bf2f(zcur[(unsigned)(n1 * 64 + lane)]);
    const float z00 = bf2f(z0q[(unsigned)(n0 * 64 + lane)]);
    const float z01 = bf2f(z0q[(unsigned)(n1 * 64 + lane)]);

    float A0 = dc0 * self0, B0 = 0.f;
    float A1 = dc1 * self1, B1 = 0.f;

    int nc0 = (m0 + 7) >> 3, nc1 = (m1 + 7) >> 3;
    int nc = nc0 > nc1 ? nc0 : nc1;
    for (int c = 0; c < nc; ++c) {
        const int j = c * 8;
        float x[8], y[8];
#pragma unroll
        for (int k = 0; k < 8; ++k) {
            unsigned r0 = (unsigned)__builtin_amdgcn_readlane(ev0.x, j + k);
            unsigned r1 = (unsigned)__builtin_amdgcn_readlane(ev1.x, j + k);
            x[k] = bf2f(zcur[(r0 << 6) + lane]);
            y[k] = bf2f(zcur[(r1 << 6) + lane]);
        }
#pragma unroll
        for (int k = 0; k < 8; ++k) {
            float w = __int_as_float(__builtin_amdgcn_readlane(ev0.y, j + k));
            float u = __int_as_float(__builtin_amdgcn_readlane(ev1.y, j + k));
            if (k & 1) { B0 = fmaf(w, x[k], B0); B1 = fmaf(u, y[k], B1); }
            else       { A0 = fmaf(w, x[k], A0); A1 = fmaf(u, y[k], A1); }
        }
    }

    // ultra-rare tail: degree > 64
    for (int e = beg0 + 64; e < end0; ++e) {
        int2 ee = cev[e];
        A0 = fmaf(__int_as_float(ee.y), bf2f(zcur[((unsigned)ee.x << 6) + lane]), A0);
    }
    for (int e = beg1 + 64; e < end1; ++e) {
        int2 ee = cev[e];
        A1 = fmaf(__int_as_float(ee.y), bf2f(zcur[((unsigned)ee.x << 6) + lane]), A1);
    }

    float res0 = 0.5f * dc0 * (A0 + B0) + 0.5f * z00;
    float res1 = 0.5f * dc1 * (A1 + B1) + 0.5f * z01;
    if (last) {
        if (lane < 40) {
            outf[(unsigned)(n0 * 40 + lane)] = res0 + b2[lane];
            outf[(unsigned)(n1 * 40 + lane)] = res1 + b2[lane];
        }
    } else {
        znb[(unsigned)(n0 * 64 + lane)] = f2bfu(res0);
        znb[(unsigned)(n1 * 64 + lane)] = f2bfu(res1);
    }
}

extern "C" void kernel_launch(void* const* d_in, const int* in_sizes, int n_in,
                              void* d_out, int out_size, void* d_ws, size_t ws_size,
                              hipStream_t stream) {
    const float* x  = (const float*)d_in[0];
    const int*   ei = (const int*)d_in[1];
    const float* W1 = (const float*)d_in[2];
    const float* b1 = (const float*)d_in[3];
    const float* W2 = (const float*)d_in[4];
    const float* b2 = (const float*)d_in[5];
    float* out = (float*)d_out;

    char* ws = (char*)d_ws;
    short*          WcT  = (short*)(ws + 0);
    float*          bc   = (float*)(ws + 49152);
    unsigned short* z0   = (unsigned short*)(ws + 65536);
    unsigned short* za   = (unsigned short*)(ws + 12865536);
    unsigned short* zb   = (unsigned short*)(ws + 25665536);
    float*          dinv = (float*)(ws + 38465536);
    int*            cnt  = (int*)(ws + 38865536);
    int*            ptr  = (int*)(ws + 39265536);
    int*            bsum = (int*)(ws + 39665664);
    int*            ptr2 = (int*)(ws + 39667712);
    int2*           cev  = (int2*)(ws + 40067840);

    hipMemsetAsync(cnt, 0, NN * sizeof(int), stream);
    wct_kernel<<<97, 256, 0, stream>>>(W1, W2, b1, WcT, bc);
    count_kernel<<<(EE + 255) / 256, 256, 0, stream>>>(ei, cnt);
    scan1<<<391, 256, 0, stream>>>(cnt, ptr, bsum);
    scan2<<<1, 512, 0, stream>>>(bsum);
    scan3<<<391, 256, 0, stream>>>(ptr, bsum, cnt, dinv, ptr2);
    gemm_z0<<<1563, 256, 0, stream>>>(x, WcT, bc, z0);
    scatter_kernel<<<(EE + 255) / 256, 256, 0, stream>>>(ei, dinv, ptr2, cev);

    propagate<<<12500, 256, 0, stream>>>(z0, z0, zb, out, ptr, cev, dinv, b2, 0);
    propagate<<<12500, 256, 0, stream>>>(zb, z0, za, out, ptr, cev, dinv, b2, 0);
    propagate<<<12500, 256, 0, stream>>>(za, z0, zb, out, ptr, cev, dinv, b2, 0);
    propagate<<<12500, 256, 0, stream>>>(zb, z0, za, out, ptr, cev, dinv, b2, 0);
    propagate<<<12500, 256, 0, stream>>>(za, z0, zb, out, ptr, cev, dinv, b2, 1);
}